// Round 1
// baseline (957.981 us; speedup 1.0000x reference)
//
#include <hip/hip_runtime.h>
#include <stdint.h>

#define NTHREADS 1024
#define NBUCKETS 4096
#define HASH_SIZE 512
#define HASH_MASK (HASH_SIZE - 1)
#define CAPMAX 2048

// ---- monotonic float<->uint mapping: larger float => larger uint ----
__device__ __forceinline__ unsigned mono_u32(float x) {
    unsigned b = __float_as_uint(x);
    return (b & 0x80000000u) ? ~b : (b | 0x80000000u);
}
__device__ __forceinline__ float inv_mono(unsigned u) {
    unsigned b = (u & 0x80000000u) ? (u & 0x7fffffffu) : ~u;
    return __uint_as_float(b);
}

// Replicate numpy op order exactly (no fma contraction):
// pen = freq*cnt + pres*(cnt>0); x = (l - (active?pen:0)) / t
__device__ __forceinline__ float compute_x(float l, int cnt, int active,
                                           float pres, float freq, float t) {
    float pen = __fadd_rn(__fmul_rn(freq, (float)cnt), (cnt > 0) ? pres : 0.0f);
    float lx = active ? __fsub_rn(l, pen) : l;
    return __fdiv_rn(lx, t);
}

__device__ __forceinline__ void hash_build(int* hkey, int* hval,
                                           const int* trow, int H, int tid) {
    for (int i = tid; i < HASH_SIZE; i += NTHREADS) { hkey[i] = -1; hval[i] = 0; }
    __syncthreads();
    for (int i = tid; i < H; i += NTHREADS) {
        int v = trow[i];
        unsigned h = ((unsigned)v * 2654435761u) >> 23;  // top 9 bits -> 512 slots
        while (true) {
            int prev = atomicCAS(&hkey[h], -1, v);
            if (prev == -1 || prev == v) { atomicAdd(&hval[h], 1); break; }
            h = (h + 1) & HASH_MASK;
        }
    }
    __syncthreads();
}

__device__ __forceinline__ int hash_lookup(const int* hkey, const int* hval, int v) {
    unsigned h = ((unsigned)v * 2654435761u) >> 23;
    while (true) {
        int kk = hkey[h];
        if (kk == v) return hval[h];
        if (kk == -1) return 0;
        h = (h + 1) & HASH_MASK;
    }
}

// ---------------- Kernel 1: histogram + bucket-level selection ----------------
__global__ __launch_bounds__(NTHREADS) void k_hist(
    const float* __restrict__ logits, const int* __restrict__ tokens,
    const float* __restrict__ pres_v, const float* __restrict__ freq_v,
    const float* __restrict__ temp_v, const float* __restrict__ topp_v,
    const int* __restrict__ topk_v, int V, int H,
    float* __restrict__ Sp_o, int* __restrict__ bstar_o,
    unsigned* __restrict__ cntA_o, float* __restrict__ sumA_o,
    int* __restrict__ lcnt_o)
{
    __shared__ int hkey[HASH_SIZE];
    __shared__ int hval[HASH_SIZE];
    __shared__ unsigned hc[NBUCKETS];
    __shared__ float hs[NBUCKETS];
    __shared__ unsigned tmp[NBUCKETS];   // reused (type-punned) for both scans
    __shared__ int bstar_s;

    int row = blockIdx.x;
    int tid = threadIdx.x;

    for (int i = tid; i < NBUCKETS; i += NTHREADS) { hc[i] = 0u; hs[i] = 0.0f; }
    if (tid == 0) bstar_s = -1;
    hash_build(hkey, hval, tokens + (size_t)row * H, H, tid);

    float pres = pres_v[row], freq = freq_v[row], t = temp_v[row];
    int active = (pres >= 1e-5f) || (freq >= 1e-5f);

    const float4* lrow = (const float4*)(logits + (size_t)row * V);
    int V4 = V >> 2;
    for (int i = tid; i < V4; i += NTHREADS) {
        float4 l4 = lrow[i];
#pragma unroll
        for (int j = 0; j < 4; ++j) {
            float l = (&l4.x)[j];
            int v = i * 4 + j;
            int cnt = hash_lookup(hkey, hval, v);
            float x = compute_x(l, cnt, active, pres, freq, t);
            unsigned u = mono_u32(x);
            unsigned b = u >> 20;
            atomicAdd(&hc[b], 1u);
            atomicAdd(&hs[b], expf(x));
        }
    }
    // scalar tail (V not multiple of 4)
    for (int v = V4 * 4 + tid; v < V; v += NTHREADS) {
        float l = logits[(size_t)row * V + v];
        int cnt = hash_lookup(hkey, hval, v);
        float x = compute_x(l, cnt, active, pres, freq, t);
        unsigned u = mono_u32(x);
        atomicAdd(&hc[u >> 20], 1u);
        atomicAdd(&hs[u >> 20], expf(x));
    }
    __syncthreads();

    // suffix-inclusive scans (descending rank order = high bucket -> low)
    for (int s = 1; s < NBUCKETS; s <<= 1) {
        for (int b = tid; b < NBUCKETS; b += NTHREADS)
            tmp[b] = hc[b] + ((b + s < NBUCKETS) ? hc[b + s] : 0u);
        __syncthreads();
        for (int b = tid; b < NBUCKETS; b += NTHREADS) hc[b] = tmp[b];
        __syncthreads();
    }
    float* tmpf = (float*)tmp;
    for (int s = 1; s < NBUCKETS; s <<= 1) {
        for (int b = tid; b < NBUCKETS; b += NTHREADS)
            tmpf[b] = hs[b] + ((b + s < NBUCKETS) ? hs[b + s] : 0.0f);
        __syncthreads();
        for (int b = tid; b < NBUCKETS; b += NTHREADS) hs[b] = tmpf[b];
        __syncthreads();
    }

    float Sp = hs[0];                     // total sum of exp(x)
    int k = topk_v[row];
    float pS = topp_v[row] * Sp;
    // bucket b fully kept iff suffix-incl count <= k AND suffix-incl sum <= p*S'
    // b* = largest b violating that (monotone predicate)
    for (int b = tid; b < NBUCKETS; b += NTHREADS) {
        if (hc[b] > (unsigned)k || hs[b] > pS) atomicMax(&bstar_s, b);
    }
    __syncthreads();
    if (tid == 0) {
        int b = bstar_s;  // always >= 0 since hc[0] = V > k
        Sp_o[row] = Sp;
        bstar_o[row] = b;
        cntA_o[row] = (b + 1 < NBUCKETS) ? hc[b + 1] : 0u;
        sumA_o[row] = (b + 1 < NBUCKETS) ? hs[b + 1] : 0.0f;
        lcnt_o[row] = 0;
    }
}

// ---------------- Kernel 2: write output + compact cut-bucket ----------------
__global__ __launch_bounds__(NTHREADS) void k_out(
    const float* __restrict__ logits, const int* __restrict__ tokens,
    const float* __restrict__ pres_v, const float* __restrict__ freq_v,
    const float* __restrict__ temp_v, int V, int H,
    const float* __restrict__ Sp_i, const int* __restrict__ bstar_i,
    int* __restrict__ lcnt_o, unsigned long long* __restrict__ list, int cap,
    float* __restrict__ out)
{
    __shared__ int hkey[HASH_SIZE];
    __shared__ int hval[HASH_SIZE];
    __shared__ int lcnt_s;

    int row = blockIdx.x;
    int tid = threadIdx.x;
    if (tid == 0) lcnt_s = 0;
    hash_build(hkey, hval, tokens + (size_t)row * H, H, tid);

    float pres = pres_v[row], freq = freq_v[row], t = temp_v[row];
    int active = (pres >= 1e-5f) || (freq >= 1e-5f);
    float Sp = Sp_i[row];
    int bst = bstar_i[row];
    unsigned long long* lst = list + (size_t)row * cap;

    const float4* lrow = (const float4*)(logits + (size_t)row * V);
    float4* orow = (float4*)(out + (size_t)row * V);
    int V4 = V >> 2;
    for (int i = tid; i < V4; i += NTHREADS) {
        float4 l4 = lrow[i];
        float4 o4;
#pragma unroll
        for (int j = 0; j < 4; ++j) {
            float l = (&l4.x)[j];
            int v = i * 4 + j;
            int cnt = hash_lookup(hkey, hval, v);
            float x = compute_x(l, cnt, active, pres, freq, t);
            unsigned u = mono_u32(x);
            int b = (int)(u >> 20);
            float o = 0.0f;
            if (b > bst) {
                o = __fdiv_rn(expf(x), Sp);
            } else if (b == bst) {
                int pos = atomicAdd(&lcnt_s, 1);
                if (pos < cap)
                    lst[pos] = ((unsigned long long)u << 32) | (unsigned)(~(unsigned)v);
            }
            (&o4.x)[j] = o;
        }
        orow[i] = o4;
    }
    for (int v = V4 * 4 + tid; v < V; v += NTHREADS) {
        float l = logits[(size_t)row * V + v];
        int cnt = hash_lookup(hkey, hval, v);
        float x = compute_x(l, cnt, active, pres, freq, t);
        unsigned u = mono_u32(x);
        int b = (int)(u >> 20);
        float o = 0.0f;
        if (b > bst) o = __fdiv_rn(expf(x), Sp);
        else if (b == bst) {
            int pos = atomicAdd(&lcnt_s, 1);
            if (pos < cap)
                lst[pos] = ((unsigned long long)u << 32) | (unsigned)(~(unsigned)v);
        }
        out[(size_t)row * V + v] = o;
    }
    __syncthreads();
    if (tid == 0) lcnt_o[row] = (lcnt_s < cap) ? lcnt_s : cap;
}

// -------- Kernel 3: exact selection within cut bucket (sort + scan) ----------
__global__ __launch_bounds__(NTHREADS) void k_sel(
    int V, const float* __restrict__ Sp_i, const unsigned* __restrict__ cntA_i,
    const float* __restrict__ sumA_i, const int* __restrict__ lcnt_i,
    const unsigned long long* __restrict__ list, int cap,
    const float* __restrict__ topp_v, const int* __restrict__ topk_v,
    float* __restrict__ out)
{
    __shared__ unsigned long long skey[CAPMAX];
    __shared__ float se[CAPMAX];
    __shared__ float sp[CAPMAX];

    int row = blockIdx.x;
    int tid = threadIdx.x;
    int count = lcnt_i[row];
    if (count > cap) count = cap;
    if (count > CAPMAX) count = CAPMAX;
    if (count == 0) return;

    int m = 1;
    while (m < count) m <<= 1;

    const unsigned long long* lr = list + (size_t)row * cap;
    for (int j = tid; j < m; j += NTHREADS)
        skey[j] = (j < count) ? lr[j] : 0ull;
    __syncthreads();

    // bitonic sort, DESCENDING on key = (u << 32) | ~idx  (=> u desc, idx asc)
    for (int kk = 2; kk <= m; kk <<= 1) {
        for (int jj = kk >> 1; jj > 0; jj >>= 1) {
            for (int i = tid; i < m; i += NTHREADS) {
                int ixj = i ^ jj;
                if (ixj > i) {
                    unsigned long long a = skey[i], b = skey[ixj];
                    bool up = ((i & kk) != 0);  // flipped -> overall descending
                    if ((a > b) == up) { skey[i] = b; skey[ixj] = a; }
                }
            }
            __syncthreads();
        }
    }

    // probs of sorted elements; pad with zeros
    for (int j = tid; j < m; j += NTHREADS) {
        float e = 0.0f;
        if (j < count) {
            unsigned u = (unsigned)(skey[j] >> 32);
            e = expf(inv_mono(u));
        }
        se[j] = e;
    }
    __syncthreads();
    // Hillis-Steele inclusive prefix scan over m
    for (int s = 1; s < m; s <<= 1) {
        for (int j = tid; j < m; j += NTHREADS)
            sp[j] = se[j] + ((j >= s) ? se[j - s] : 0.0f);
        __syncthreads();
        for (int j = tid; j < m; j += NTHREADS) se[j] = sp[j];
        __syncthreads();
    }

    float Sp = Sp_i[row];
    unsigned cntA = cntA_i[row];
    float sumA = sumA_i[row];
    int k = topk_v[row];
    float pS = topp_v[row] * Sp;

    for (int j = tid; j < count; j += NTHREADS) {
        unsigned long long key = skey[j];
        unsigned u = (unsigned)(key >> 32);
        unsigned idx = ~(unsigned)(key & 0xffffffffull);
        float e = expf(inv_mono(u));
        float incl = sumA + se[j];
        float excl = __fsub_rn(incl, e);   // mirrors (cumsum - probs_sort)
        bool keep = ((cntA + (unsigned)j) < (unsigned)k) && (excl <= pS);
        if (keep) out[(size_t)row * V + idx] = __fdiv_rn(e, Sp);
    }
}

extern "C" void kernel_launch(void* const* d_in, const int* in_sizes, int n_in,
                              void* d_out, int out_size, void* d_ws, size_t ws_size,
                              hipStream_t stream) {
    const float* logits = (const float*)d_in[0];
    const float* pres   = (const float*)d_in[1];
    const float* freq   = (const float*)d_in[2];
    const float* temps  = (const float*)d_in[3];
    const float* topps  = (const float*)d_in[4];
    const int*   tokens = (const int*)d_in[5];
    const int*   topks  = (const int*)d_in[6];
    int N = in_sizes[1];
    int V = in_sizes[0] / N;
    int H = in_sizes[5] / N;
    float* out = (float*)d_out;

    char* ws = (char*)d_ws;
    float*    Sp    = (float*)ws;
    int*      bstar = (int*)(ws + 4 * (size_t)N);
    unsigned* cntA  = (unsigned*)(ws + 8 * (size_t)N);
    float*    sumA  = (float*)(ws + 12 * (size_t)N);
    int*      lcnt  = (int*)(ws + 16 * (size_t)N);
    size_t list_off = ((size_t)20 * N + 7) & ~(size_t)7;
    unsigned long long* list = (unsigned long long*)(ws + list_off);

    long long avail = ((long long)ws_size - (long long)list_off) / ((long long)N * 8);
    int cap = (int)((avail > (long long)CAPMAX) ? CAPMAX : (avail > 0 ? avail : 0));

    k_hist<<<N, NTHREADS, 0, stream>>>(logits, tokens, pres, freq, temps, topps,
                                       topks, V, H, Sp, bstar, cntA, sumA, lcnt);
    k_out<<<N, NTHREADS, 0, stream>>>(logits, tokens, pres, freq, temps, V, H,
                                      Sp, bstar, lcnt, list, cap, out);
    k_sel<<<N, NTHREADS, 0, stream>>>(V, Sp, cntA, sumA, lcnt, list, cap,
                                      topps, topks, out);
}

// Round 2
// 570.528 us; speedup vs baseline: 1.6791x; 1.6791x over previous
//
#include <hip/hip_runtime.h>
#include <stdint.h>

#define NB 8192          // histogram buckets (sign+exp+4 mantissa bits)
#define BSHIFT 19        // 32-13
#define HASH_SIZE 512
#define HASH_MASK 511
#define CAPMAX 4096
#define S1 8             // k_hist blocks per row
#define S2 16            // k_out blocks per row

typedef unsigned long long ull;

// ---- monotonic float<->uint mapping: larger float => larger uint ----
__device__ __forceinline__ unsigned mono_u32(float x) {
    unsigned b = __float_as_uint(x);
    return (b & 0x80000000u) ? ~b : (b | 0x80000000u);
}
__device__ __forceinline__ float inv_mono(unsigned u) {
    unsigned b = (u & 0x80000000u) ? (u & 0x7fffffffu) : ~u;
    return __uint_as_float(b);
}

// numpy op order: pen = freq*cnt + pres*(cnt>0); x = (l - (active?pen:0)) / t
__device__ __forceinline__ float compute_x(float l, int cnt, int active,
                                           float pres, float freq, float t) {
    float pen = __fadd_rn(__fmul_rn(freq, (float)cnt), (cnt > 0) ? pres : 0.0f);
    float lx = active ? __fsub_rn(l, pen) : l;
    return __fdiv_rn(lx, t);
}

__device__ __forceinline__ void hash_build(int* hkey, int* hval,
                                           const int* trow, int H,
                                           int tid, int nthr) {
    for (int i = tid; i < HASH_SIZE; i += nthr) { hkey[i] = -1; hval[i] = 0; }
    __syncthreads();
    for (int i = tid; i < H; i += nthr) {
        int v = trow[i];
        unsigned h = ((unsigned)v * 2654435761u) >> 23;
        while (true) {
            int prev = atomicCAS(&hkey[h], -1, v);
            if (prev == -1 || prev == v) { atomicAdd(&hval[h], 1); break; }
            h = (h + 1) & HASH_MASK;
        }
    }
    __syncthreads();
}

__device__ __forceinline__ int hash_lookup(const int* hkey, const int* hval, int v) {
    unsigned h = ((unsigned)v * 2654435761u) >> 23;
    while (true) {
        int kk = hkey[h];
        if (kk == v) return hval[h];
        if (kk == -1) return 0;
        h = (h + 1) & HASH_MASK;
    }
}

// ---- Pass 1: unpenalized count histogram + sum(exp) per row ----
__global__ __launch_bounds__(256) void k_hist(
    const float* __restrict__ logits, const float* __restrict__ temps,
    int V, unsigned* __restrict__ rowhist, float* __restrict__ Sp)
{
    __shared__ unsigned hc[NB];
    __shared__ float wsum[4];
    int row = blockIdx.x / S1, seg = blockIdx.x % S1;
    int tid = threadIdx.x;
    for (int b = tid; b < NB; b += 256) hc[b] = 0u;
    __syncthreads();

    float t = temps[row];
    const float* lrow = logits + (size_t)row * V;
    int chunk4 = (V + 4 * S1 - 1) / (4 * S1);
    int start = seg * chunk4 * 4;
    int end = min(V, start + chunk4 * 4);
    float es = 0.0f;
    if (start < end) {
        int n4 = (end - start) >> 2;
        const float4* l4p = (const float4*)(lrow + start);
        for (int i = tid; i < n4; i += 256) {
            float4 l4 = l4p[i];
#pragma unroll
            for (int j = 0; j < 4; ++j) {
                float x = __fdiv_rn((&l4.x)[j], t);
                unsigned u = mono_u32(x);
                atomicAdd(&hc[u >> BSHIFT], 1u);
                es += __expf(x);
            }
        }
        for (int v = start + n4 * 4 + tid; v < end; v += 256) {
            float x = __fdiv_rn(lrow[v], t);
            atomicAdd(&hc[mono_u32(x) >> BSHIFT], 1u);
            es += __expf(x);
        }
    }
    for (int off = 32; off > 0; off >>= 1) es += __shfl_down(es, off);
    if ((tid & 63) == 0) wsum[tid >> 6] = es;
    __syncthreads();
    if (tid == 0) atomicAdd(&Sp[row], wsum[0] + wsum[1] + wsum[2] + wsum[3]);

    unsigned* rh = rowhist + (size_t)row * NB;
    for (int b = tid; b < NB; b += 256) {
        unsigned c = hc[b];
        if (c) atomicAdd(&rh[b], c);
    }
}

// ---- Pass 2 (per row): penalty corrections + suffix scan + cut bucket ----
__global__ __launch_bounds__(256) void k_cut(
    const float* __restrict__ logits, const int* __restrict__ tokens,
    const float* __restrict__ pres_v, const float* __restrict__ freq_v,
    const float* __restrict__ temps, const int* __restrict__ topks,
    int V, int H, unsigned* __restrict__ rowhist, float* __restrict__ Sp,
    int* __restrict__ bstar)
{
    __shared__ unsigned hc[NB];
    __shared__ int hkey[HASH_SIZE], hval[HASH_SIZE];
    __shared__ int sct[256], sct2[256];
    __shared__ float wsum[4];
    __shared__ int bstar_s;
    int row = blockIdx.x, tid = threadIdx.x;
    unsigned* rh = rowhist + (size_t)row * NB;
    for (int b = tid; b < NB; b += 256) hc[b] = rh[b];
    if (tid == 0) bstar_s = -1;
    hash_build(hkey, hval, tokens + (size_t)row * H, H, tid, 256);

    float t = temps[row], pres = pres_v[row], freq = freq_v[row];
    int active = (pres >= 1e-5f) || (freq >= 1e-5f);
    float corr = 0.0f;
    if (active) {
        for (int s = tid; s < HASH_SIZE; s += 256) {
            int v = hkey[s];
            if (v >= 0) {
                int c = hval[s];
                float l = logits[(size_t)row * V + v];
                float x0 = __fdiv_rn(l, t);
                float xp = compute_x(l, c, 1, pres, freq, t);
                unsigned b0 = mono_u32(x0) >> BSHIFT;
                unsigned bp = mono_u32(xp) >> BSHIFT;
                if (b0 != bp) { atomicSub(&hc[b0], 1u); atomicAdd(&hc[bp], 1u); }
                corr += __expf(xp) - __expf(x0);
            }
        }
    }
    for (int off = 32; off > 0; off >>= 1) corr += __shfl_down(corr, off);
    if ((tid & 63) == 0) wsum[tid >> 6] = corr;
    __syncthreads();   // also makes hc corrections visible
    if (tid == 0) Sp[row] = Sp[row] + (wsum[0] + wsum[1] + wsum[2] + wsum[3]);
    __syncthreads();

    // per-thread serial suffix over its 32 buckets, then block suffix scan
    int base = tid * 32;
    int acc = 0;
    for (int q = 31; q >= 0; --q) { acc += (int)hc[base + q]; hc[base + q] = (unsigned)acc; }
    sct[tid] = acc;
    __syncthreads();
    int* a = sct; int* b2 = sct2;
    for (int s = 1; s < 256; s <<= 1) {
        int v = a[tid] + ((tid + s < 256) ? a[tid + s] : 0);
        __syncthreads();
        b2[tid] = v;
        __syncthreads();
        int* tmp = a; a = b2; b2 = tmp;
    }
    int above = (tid < 255) ? a[tid + 1] : 0;
    int k = topks[row];
    int best = -1;
    for (int q = 0; q < 32; ++q) {
        int sc = (int)hc[base + q] + above;
        if (sc >= k) best = base + q;   // max b with suffix-count >= k
    }
    if (best >= 0) atomicMax(&bstar_s, best);
    __syncthreads();
    if (tid == 0) bstar[row] = bstar_s;
}

// ---- Pass 3: zero-fill output + compact candidate (u, idx) ----
__global__ __launch_bounds__(256) void k_out(
    const float* __restrict__ logits, const float* __restrict__ temps,
    int V, const int* __restrict__ bstar, int* __restrict__ lcnt,
    ull* __restrict__ list, int cap, float* __restrict__ out)
{
    int row = blockIdx.x / S2, seg = blockIdx.x % S2;
    int tid = threadIdx.x;
    float t = temps[row];
    int bst = bstar[row];
    const float* lrow = logits + (size_t)row * V;
    float* orow = out + (size_t)row * V;
    int chunk4 = (V + 4 * S2 - 1) / (4 * S2);
    int start = seg * chunk4 * 4;
    int end = min(V, start + chunk4 * 4);
    ull* lst = list + (size_t)row * cap;
    if (start >= end) return;
    int n4 = (end - start) >> 2;
    const float4* l4p = (const float4*)(lrow + start);
    float4* o4p = (float4*)(orow + start);
    const float4 z4 = make_float4(0.f, 0.f, 0.f, 0.f);
    for (int i = tid; i < n4; i += 256) {
        float4 l4 = l4p[i];
        o4p[i] = z4;
#pragma unroll
        for (int j = 0; j < 4; ++j) {
            float x = __fdiv_rn((&l4.x)[j], t);
            unsigned u = mono_u32(x);
            if ((int)(u >> BSHIFT) >= bst) {
                int v = start + i * 4 + j;
                int pos = atomicAdd(&lcnt[row], 1);
                if (pos < cap) lst[pos] = ((ull)u << 32) | (unsigned)(~(unsigned)v);
            }
        }
    }
    for (int v = start + n4 * 4 + tid; v < end; v += 256) {
        float x = __fdiv_rn(lrow[v], t);
        unsigned u = mono_u32(x);
        orow[v] = 0.0f;
        if ((int)(u >> BSHIFT) >= bst) {
            int pos = atomicAdd(&lcnt[row], 1);
            if (pos < cap) lst[pos] = ((ull)u << 32) | (unsigned)(~(unsigned)v);
        }
    }
}

// ---- Pass 4: fix penalized candidates, sort, exact cumsum, scatter kept ----
__global__ __launch_bounds__(1024) void k_sel(
    const float* __restrict__ logits, const int* __restrict__ tokens,
    const float* __restrict__ pres_v, const float* __restrict__ freq_v,
    const float* __restrict__ temps, const float* __restrict__ topp_v,
    const int* __restrict__ topk_v, int V, int H,
    const float* __restrict__ Sp_i, const int* __restrict__ lcnt,
    const ull* __restrict__ list, int cap, float* __restrict__ out)
{
    __shared__ ull skey[CAPMAX];
    __shared__ float se[CAPMAX];
    __shared__ float bs1[1024], bs2[1024];
    __shared__ int hkey[HASH_SIZE], hval[HASH_SIZE];
    int row = blockIdx.x, tid = threadIdx.x;
    int count = lcnt[row];
    if (count > cap) count = cap;
    if (count > CAPMAX) count = CAPMAX;
    hash_build(hkey, hval, tokens + (size_t)row * H, H, tid, 1024);

    float t = temps[row], pres = pres_v[row], freq = freq_v[row];
    int active = (pres >= 1e-5f) || (freq >= 1e-5f);
    int m = 1; while (m < count) m <<= 1;
    const ull* lr = list + (size_t)row * cap;
    for (int j = tid; j < m; j += 1024) {
        ull key = 0ull;
        if (j < count) {
            key = lr[j];
            if (active) {
                unsigned idx = ~(unsigned)(key & 0xffffffffull);
                int c = hash_lookup(hkey, hval, (int)idx);
                if (c > 0) {   // penalized: recompute exact value
                    float l = logits[(size_t)row * V + idx];
                    float xp = compute_x(l, c, 1, pres, freq, t);
                    key = ((ull)mono_u32(xp) << 32) | (unsigned)(~idx);
                }
            }
        }
        skey[j] = key;
    }
    __syncthreads();

    // bitonic sort descending on (u desc, idx asc)
    for (int kk = 2; kk <= m; kk <<= 1) {
        for (int jj = kk >> 1; jj > 0; jj >>= 1) {
            for (int i = tid; i < m; i += 1024) {
                int ixj = i ^ jj;
                if (ixj > i) {
                    ull a = skey[i], b = skey[ixj];
                    bool up = ((i & kk) != 0);
                    if ((a > b) == up) { skey[i] = b; skey[ixj] = a; }
                }
            }
            __syncthreads();
        }
    }

    for (int j = tid; j < CAPMAX; j += 1024)
        se[j] = (j < count) ? __expf(inv_mono((unsigned)(skey[j] >> 32))) : 0.0f;
    __syncthreads();

    // inclusive scan over 4096: 4-serial per thread + block scan of totals
    int j0 = tid * 4;
    float e0 = se[j0], e1 = se[j0 + 1], e2 = se[j0 + 2], e3 = se[j0 + 3];
    float c0 = e0, c1 = c0 + e1, c2 = c1 + e2, c3 = c2 + e3;
    bs1[tid] = c3;
    __syncthreads();
    float* a = bs1; float* b2 = bs2;
    for (int s = 1; s < 1024; s <<= 1) {
        float v = a[tid] + ((tid >= s) ? a[tid - s] : 0.0f);
        __syncthreads();
        b2[tid] = v;
        __syncthreads();
        float* tmp = a; a = b2; b2 = tmp;
    }
    float pre = (tid > 0) ? a[tid - 1] : 0.0f;

    float Sp = Sp_i[row];
    float pS = topp_v[row] * Sp;
    int k = topk_v[row];
    float inc[4] = {pre + c0, pre + c1, pre + c2, pre + c3};
    float ee[4] = {e0, e1, e2, e3};
#pragma unroll
    for (int q = 0; q < 4; ++q) {
        int j = j0 + q;
        if (j < count) {
            float e = ee[q];
            float excl = __fsub_rn(inc[q], e);
            if ((j < k) && (excl <= pS)) {
                unsigned idx = ~(unsigned)(skey[j] & 0xffffffffull);
                out[(size_t)row * V + idx] = __fdiv_rn(e, Sp);
            }
        }
    }
}

extern "C" void kernel_launch(void* const* d_in, const int* in_sizes, int n_in,
                              void* d_out, int out_size, void* d_ws, size_t ws_size,
                              hipStream_t stream) {
    const float* logits = (const float*)d_in[0];
    const float* pres   = (const float*)d_in[1];
    const float* freq   = (const float*)d_in[2];
    const float* temps  = (const float*)d_in[3];
    const float* topps  = (const float*)d_in[4];
    const int*   tokens = (const int*)d_in[5];
    const int*   topks  = (const int*)d_in[6];
    int N = in_sizes[1];
    int V = in_sizes[0] / N;
    int H = in_sizes[5] / N;
    float* out = (float*)d_out;

    char* ws = (char*)d_ws;
    float*    Sp      = (float*)ws;                         // N f32
    int*      lcnt    = (int*)(ws + 4 * (size_t)N);         // N i32
    int*      bstar   = (int*)(ws + 8 * (size_t)N);         // N i32
    unsigned* rowhist = (unsigned*)(ws + 12 * (size_t)N);   // N*NB u32
    size_t list_off = 12 * (size_t)N + (size_t)N * NB * 4;
    ull* list = (ull*)(ws + list_off);

    long long avail = ((long long)ws_size - (long long)list_off) / ((long long)N * 8);
    int cap = (int)((avail > (long long)CAPMAX) ? CAPMAX : (avail > 0 ? avail : 0));

    size_t zbytes = list_off;   // Sp, lcnt, bstar, rowhist
    if (zbytes > ws_size) zbytes = ws_size;
    hipMemsetAsync(d_ws, 0, zbytes, stream);

    k_hist<<<N * S1, 256, 0, stream>>>(logits, temps, V, rowhist, Sp);
    k_cut<<<N, 256, 0, stream>>>(logits, tokens, pres, freq, temps, topks,
                                 V, H, rowhist, Sp, bstar);
    k_out<<<N * S2, 256, 0, stream>>>(logits, temps, V, bstar, lcnt, list, cap, out);
    k_sel<<<N, 1024, 0, stream>>>(logits, tokens, pres, freq, temps, topps, topks,
                                  V, H, Sp, lcnt, list, cap, out);
}

// Round 3
// 327.104 us; speedup vs baseline: 2.9287x; 1.7442x over previous
//
#include <hip/hip_runtime.h>
#include <stdint.h>

#define NB 8192          // histogram buckets (sign+exp+4 mantissa bits)
#define BSHIFT 19
#define HS 512
#define HM 511
#define CAP 4096
#define NT 1024

typedef unsigned long long ull;

// ---- monotonic float<->uint mapping: larger float => larger uint ----
__device__ __forceinline__ unsigned mono_u32(float x) {
    unsigned b = __float_as_uint(x);
    return (b & 0x80000000u) ? ~b : (b | 0x80000000u);
}
__device__ __forceinline__ float inv_mono(unsigned u) {
    unsigned b = (u & 0x80000000u) ? (u & 0x7fffffffu) : ~u;
    return __uint_as_float(b);
}

// numpy op order: pen = freq*cnt + pres*(cnt>0); x = (l - pen) / t
__device__ __forceinline__ float compute_x(float l, int cnt,
                                           float pres, float freq, float t) {
    float pen = __fadd_rn(__fmul_rn(freq, (float)cnt), (cnt > 0) ? pres : 0.0f);
    return __fdiv_rn(__fsub_rn(l, pen), t);
}

__device__ __forceinline__ void hash_build(int* hkey, int* hval,
                                           const int* trow, int H, int tid) {
    for (int i = tid; i < HS; i += NT) { hkey[i] = -1; hval[i] = 0; }
    __syncthreads();
    for (int i = tid; i < H; i += NT) {
        int v = trow[i];
        unsigned h = ((unsigned)v * 2654435761u) >> 23;
        while (true) {
            int prev = atomicCAS(&hkey[h], -1, v);
            if (prev == -1 || prev == v) { atomicAdd(&hval[h], 1); break; }
            h = (h + 1) & HM;
        }
    }
    __syncthreads();
}

__device__ __forceinline__ int hash_lookup(const int* hkey, const int* hval, int v) {
    unsigned h = ((unsigned)v * 2654435761u) >> 23;
    while (true) {
        int kk = hkey[h];
        if (kk == v) return hval[h];
        if (kk == -1) return 0;
        h = (h + 1) & HM;
    }
}

// ---- Pass 1 (one block per row): histogram + Sexp + corrections + cut ----
__global__ __launch_bounds__(NT) void k_pass1(
    const float* __restrict__ logits, const int* __restrict__ tokens,
    const float* __restrict__ pres_v, const float* __restrict__ freq_v,
    const float* __restrict__ temps, const int* __restrict__ topks,
    int V, int H, float* __restrict__ Sp_o, int* __restrict__ bstar_o)
{
    __shared__ unsigned hc[NB];                 // 32 KB
    __shared__ int hkey[HS], hval[HS];          // 4 KB
    __shared__ int sct[NT], sct2[NT];           // 8 KB
    __shared__ float esum_s, corr_s;
    __shared__ int bstar_s;

    int row = blockIdx.x, tid = threadIdx.x;
    for (int b = tid; b < NB; b += NT) hc[b] = 0u;
    if (tid == 0) { esum_s = 0.0f; corr_s = 0.0f; bstar_s = -1; }
    hash_build(hkey, hval, tokens + (size_t)row * H, H, tid);  // syncs cover init

    float t = temps[row];
    float r = __fdiv_rn(1.0f, t);     // identical in both passes
    const float4* l4p = (const float4*)(logits + (size_t)row * V);
    int V4 = V >> 2;
    float es = 0.0f;
    int i = tid;
    for (; i + 3 * NT < V4; i += 4 * NT) {
        float4 A = l4p[i], B = l4p[i + NT], C = l4p[i + 2 * NT], D = l4p[i + 3 * NT];
        float4 arr[4] = {A, B, C, D};
#pragma unroll
        for (int q = 0; q < 4; ++q)
#pragma unroll
            for (int j = 0; j < 4; ++j) {
                float x = __fmul_rn((&arr[q].x)[j], r);
                atomicAdd(&hc[mono_u32(x) >> BSHIFT], 1u);
                es += __expf(x);
            }
    }
    for (; i < V4; i += NT) {
        float4 A = l4p[i];
#pragma unroll
        for (int j = 0; j < 4; ++j) {
            float x = __fmul_rn((&A.x)[j], r);
            atomicAdd(&hc[mono_u32(x) >> BSHIFT], 1u);
            es += __expf(x);
        }
    }
    for (int v = (V4 << 2) + tid; v < V; v += NT) {
        float x = __fmul_rn(logits[(size_t)row * V + v], r);
        atomicAdd(&hc[mono_u32(x) >> BSHIFT], 1u);
        es += __expf(x);
    }
    for (int off = 32; off; off >>= 1) es += __shfl_down(es, off);
    if ((tid & 63) == 0) atomicAdd(&esum_s, es);
    __syncthreads();   // histogram complete

    float pres = pres_v[row], freq = freq_v[row];
    int active = (pres >= 1e-5f) || (freq >= 1e-5f);
    float corr = 0.0f;
    if (active) {
        for (int s = tid; s < HS; s += NT) {
            int v = hkey[s];
            if (v >= 0) {
                int c = hval[s];
                float l = logits[(size_t)row * V + v];
                float x0 = __fmul_rn(l, r);              // matches stream phase
                float xp = compute_x(l, c, pres, freq, t);  // exact penalized
                unsigned b0 = mono_u32(x0) >> BSHIFT;
                unsigned bp = mono_u32(xp) >> BSHIFT;
                if (b0 != bp) { atomicSub(&hc[b0], 1u); atomicAdd(&hc[bp], 1u); }
                corr += __expf(xp) - __expf(x0);
            }
        }
    }
    for (int off = 32; off; off >>= 1) corr += __shfl_down(corr, off);
    if ((tid & 63) == 0) atomicAdd(&corr_s, corr);
    __syncthreads();   // corrections complete

    // suffix scan: 8 buckets per thread serial, then block suffix scan
    const int BPT = NB / NT;   // 8
    int base = tid * BPT;
    int acc = 0;
#pragma unroll
    for (int q = BPT - 1; q >= 0; --q) { acc += (int)hc[base + q]; hc[base + q] = (unsigned)acc; }
    sct[tid] = acc;
    __syncthreads();
    int* a = sct; int* b2 = sct2;
    for (int s = 1; s < NT; s <<= 1) {
        int v = a[tid] + ((tid + s < NT) ? a[tid + s] : 0);
        __syncthreads();
        b2[tid] = v;
        __syncthreads();
        int* tmp = a; a = b2; b2 = tmp;
    }
    int above = (tid < NT - 1) ? a[tid + 1] : 0;
    int k = topks[row];
    int best = -1;
#pragma unroll
    for (int q = BPT - 1; q >= 0; --q)
        if ((int)hc[base + q] + above >= k) { best = base + q; break; }
    if (best >= 0) atomicMax(&bstar_s, best);
    __syncthreads();
    if (tid == 0) {
        Sp_o[row] = esum_s + corr_s;
        bstar_o[row] = bstar_s;
    }
}

// ---- Pass 2 (one block per row): zero-fill + compact + sort + select ----
__global__ __launch_bounds__(NT) void k_pass2(
    const float* __restrict__ logits, const int* __restrict__ tokens,
    const float* __restrict__ pres_v, const float* __restrict__ freq_v,
    const float* __restrict__ temps, const float* __restrict__ topp_v,
    const int* __restrict__ topk_v, int V, int H,
    const float* __restrict__ Sp_i, const int* __restrict__ bstar_i,
    float* __restrict__ out)
{
    __shared__ ull skey[CAP];                   // 32 KB
    __shared__ float se[CAP];                   // 16 KB
    __shared__ float bs1[NT], bs2[NT];          // 8 KB
    __shared__ int hkey[HS], hval[HS];          // 4 KB
    __shared__ int lcnt_s;

    int row = blockIdx.x, tid = threadIdx.x;
    if (tid == 0) lcnt_s = 0;
    hash_build(hkey, hval, tokens + (size_t)row * H, H, tid);

    float t = temps[row];
    float r = __fdiv_rn(1.0f, t);
    int bst = bstar_i[row] - 2;               // 2-bucket slack for approx bucketing
    if (bst < 0) bst = 0;
    const float4* l4p = (const float4*)(logits + (size_t)row * V);
    float4* o4p = (float4*)(out + (size_t)row * V);
    int V4 = V >> 2;
    const float4 z4 = make_float4(0.f, 0.f, 0.f, 0.f);

    int i = tid;
    for (; i + 3 * NT < V4; i += 4 * NT) {
        float4 A = l4p[i], B = l4p[i + NT], C = l4p[i + 2 * NT], D = l4p[i + 3 * NT];
        o4p[i] = z4; o4p[i + NT] = z4; o4p[i + 2 * NT] = z4; o4p[i + 3 * NT] = z4;
        float4 arr[4] = {A, B, C, D};
#pragma unroll
        for (int q = 0; q < 4; ++q) {
            int vb = (i + q * NT) << 2;
#pragma unroll
            for (int j = 0; j < 4; ++j) {
                float l = (&arr[q].x)[j];
                unsigned ua = mono_u32(__fmul_rn(l, r));
                if ((int)(ua >> BSHIFT) >= bst) {
                    unsigned ue = mono_u32(__fdiv_rn(l, t));   // exact key
                    int pos = atomicAdd(&lcnt_s, 1);
                    if (pos < CAP)
                        skey[pos] = ((ull)ue << 32) | (unsigned)~(unsigned)(vb + j);
                }
            }
        }
    }
    for (; i < V4; i += NT) {
        float4 A = l4p[i];
        o4p[i] = z4;
#pragma unroll
        for (int j = 0; j < 4; ++j) {
            float l = (&A.x)[j];
            unsigned ua = mono_u32(__fmul_rn(l, r));
            if ((int)(ua >> BSHIFT) >= bst) {
                unsigned ue = mono_u32(__fdiv_rn(l, t));
                int pos = atomicAdd(&lcnt_s, 1);
                if (pos < CAP)
                    skey[pos] = ((ull)ue << 32) | (unsigned)~(unsigned)((i << 2) + j);
            }
        }
    }
    for (int v = (V4 << 2) + tid; v < V; v += NT) {
        float l = logits[(size_t)row * V + v];
        out[(size_t)row * V + v] = 0.0f;
        unsigned ua = mono_u32(__fmul_rn(l, r));
        if ((int)(ua >> BSHIFT) >= bst) {
            unsigned ue = mono_u32(__fdiv_rn(l, t));
            int pos = atomicAdd(&lcnt_s, 1);
            if (pos < CAP)
                skey[pos] = ((ull)ue << 32) | (unsigned)~(unsigned)v;
        }
    }
    __syncthreads();
    int count = lcnt_s; if (count > CAP) count = CAP;

    float pres = pres_v[row], freq = freq_v[row];
    int active = (pres >= 1e-5f) || (freq >= 1e-5f);
    if (active) {
        for (int j = tid; j < count; j += NT) {
            unsigned idx = ~(unsigned)(skey[j] & 0xffffffffull);
            int c = hash_lookup(hkey, hval, (int)idx);
            if (c > 0) {
                float l = logits[(size_t)row * V + idx];
                float xp = compute_x(l, c, pres, freq, t);
                skey[j] = ((ull)mono_u32(xp) << 32) | (unsigned)~idx;
            }
        }
    }
    int m = 1; while (m < count) m <<= 1;
    for (int j = count + tid; j < m; j += NT) skey[j] = 0ull;
    __syncthreads();

    // bitonic sort descending on (u desc, idx asc)
    for (int kk = 2; kk <= m; kk <<= 1) {
        for (int jj = kk >> 1; jj > 0; jj >>= 1) {
            for (int i2 = tid; i2 < m; i2 += NT) {
                int ixj = i2 ^ jj;
                if (ixj > i2) {
                    ull A = skey[i2], B = skey[ixj];
                    bool up = ((i2 & kk) != 0);
                    if ((A > B) == up) { skey[i2] = B; skey[ixj] = A; }
                }
            }
            __syncthreads();
        }
    }

    for (int j = tid; j < CAP; j += NT)
        se[j] = (j < count) ? __expf(inv_mono((unsigned)(skey[j] >> 32))) : 0.0f;
    __syncthreads();

    // inclusive scan over CAP: 4 serial per thread + block scan of totals
    int j0 = tid << 2;
    float e0 = se[j0], e1 = se[j0 + 1], e2 = se[j0 + 2], e3 = se[j0 + 3];
    float c0 = e0, c1 = c0 + e1, c2 = c1 + e2, c3 = c2 + e3;
    bs1[tid] = c3;
    __syncthreads();
    float* a = bs1; float* b2 = bs2;
    for (int s = 1; s < NT; s <<= 1) {
        float v = a[tid] + ((tid >= s) ? a[tid - s] : 0.0f);
        __syncthreads();
        b2[tid] = v;
        __syncthreads();
        float* tmp = a; a = b2; b2 = tmp;
    }
    float pre = (tid > 0) ? a[tid - 1] : 0.0f;

    float Sp = Sp_i[row];
    float pS = topp_v[row] * Sp;
    int k = topk_v[row];
    float inc[4] = {pre + c0, pre + c1, pre + c2, pre + c3};
    float ee[4] = {e0, e1, e2, e3};
#pragma unroll
    for (int q = 0; q < 4; ++q) {
        int j = j0 + q;
        if (j < count) {
            float e = ee[q];
            float excl = __fsub_rn(inc[q], e);
            if ((j < k) && (excl <= pS)) {
                unsigned idx = ~(unsigned)(skey[j] & 0xffffffffull);
                out[(size_t)row * V + idx] = __fdiv_rn(e, Sp);
            }
        }
    }
}

extern "C" void kernel_launch(void* const* d_in, const int* in_sizes, int n_in,
                              void* d_out, int out_size, void* d_ws, size_t ws_size,
                              hipStream_t stream) {
    const float* logits = (const float*)d_in[0];
    const float* pres   = (const float*)d_in[1];
    const float* freq   = (const float*)d_in[2];
    const float* temps  = (const float*)d_in[3];
    const float* topps  = (const float*)d_in[4];
    const int*   tokens = (const int*)d_in[5];
    const int*   topks  = (const int*)d_in[6];
    int N = in_sizes[1];
    int V = in_sizes[0] / N;
    int H = in_sizes[5] / N;
    float* out = (float*)d_out;

    char* ws = (char*)d_ws;
    float* Sp    = (float*)ws;                 // N f32
    int*   bstar = (int*)(ws + 4 * (size_t)N); // N i32

    k_pass1<<<N, NT, 0, stream>>>(logits, tokens, pres, freq, temps, topks,
                                  V, H, Sp, bstar);
    k_pass2<<<N, NT, 0, stream>>>(logits, tokens, pres, freq, temps, topps, topks,
                                  V, H, Sp, bstar, out);
}

// Round 4
// 295.801 us; speedup vs baseline: 3.2386x; 1.1058x over previous
//
#include <hip/hip_runtime.h>
#include <stdint.h>

#define NB 8192          // coarse buckets (top 13 bits of monotone key)
#define BSHIFT 19
#define HS 512
#define HM 511
#define CAP 4096         // candidate capacity
#define PCAP 2048        // pruned-candidate capacity
#define NRB 2048         // refined buckets
#define NT 1024

typedef unsigned long long ull;

// ---- monotonic float<->uint mapping: larger float => larger uint ----
__device__ __forceinline__ unsigned mono_u32(float x) {
    unsigned b = __float_as_uint(x);
    return (b & 0x80000000u) ? ~b : (b | 0x80000000u);
}
__device__ __forceinline__ float inv_mono(unsigned u) {
    unsigned b = (u & 0x80000000u) ? (u & 0x7fffffffu) : ~u;
    return __uint_as_float(b);
}

// numpy op order: pen = freq*cnt + pres*(cnt>0); x = (l - pen) / t
__device__ __forceinline__ float compute_x(float l, int cnt,
                                           float pres, float freq, float t) {
    float pen = __fadd_rn(__fmul_rn(freq, (float)cnt), (cnt > 0) ? pres : 0.0f);
    return __fdiv_rn(__fsub_rn(l, pen), t);
}

__global__ __launch_bounds__(NT) void k_fused(
    const float* __restrict__ logits, const int* __restrict__ tokens,
    const float* __restrict__ pres_v, const float* __restrict__ freq_v,
    const float* __restrict__ temps, const float* __restrict__ topp_v,
    const int* __restrict__ topk_v, int V, int H, float* __restrict__ out)
{
    // ---- 60 KB LDS, phase-wise region reuse ----
    __shared__ __align__(16) char smem[(32 + 16 + 8 + 4) * 1024];
    unsigned* hc = (unsigned*)smem;              // A: coarse hist (phases A,B)
    ull* skey = (ull*)smem;                      // A alias: candidates (C..F)
    char* regB = smem + 32 * 1024;               // 16 KB
    float* se = (float*)regB;                    //   phase F exp values
    int* sct = (int*)regB;                       //   scan scratch (B, D)
    int* sct2 = (int*)(regB + 4 * 1024);
    ull* tmpc = (ull*)regB;                      //   phase D compaction buffer
    char* regC = smem + 48 * 1024;               // 8 KB
    float* bs1 = (float*)regC;                   //   phase F block scan
    float* bs2 = (float*)(regC + 4 * 1024);
    unsigned* rh = (unsigned*)regC;              //   phase D refined hist
    char* regD = smem + 56 * 1024;               // 4 KB: penalty hash
    int* hkey = (int*)regD;
    int* hval = (int*)(regD + 2 * 1024);
    __shared__ float esum_s, corr_s;
    __shared__ int bstar_s, lcnt_s, rb_s, pcnt_s;

    int row = blockIdx.x, tid = threadIdx.x;
    for (int b = tid; b < NB; b += NT) hc[b] = 0u;
    if (tid == 0) { esum_s = 0.f; corr_s = 0.f; bstar_s = -1; lcnt_s = 0; rb_s = 0; pcnt_s = 0; }

    // ---- hash of penalty tokens ----
    for (int i = tid; i < HS; i += NT) { hkey[i] = -1; hval[i] = 0; }
    __syncthreads();
    const int* trow = tokens + (size_t)row * H;
    for (int i = tid; i < H; i += NT) {
        int v = trow[i];
        unsigned h = ((unsigned)v * 2654435761u) >> 23;
        while (true) {
            int prev = atomicCAS(&hkey[h], -1, v);
            if (prev == -1 || prev == v) { atomicAdd(&hval[h], 1); break; }
            h = (h + 1) & HM;
        }
    }
    __syncthreads();

    float t = temps[row];
    float r = __fdiv_rn(1.0f, t);          // identical approx in both streams
    const float* lrow = logits + (size_t)row * V;
    const float4* l4p = (const float4*)lrow;
    int V4 = V >> 2;

    // ---- Phase A: stream 1 — coarse histogram + sum(exp), 8-deep unroll ----
    float es = 0.0f;
    int i = tid;
    for (; i + 7 * NT < V4; i += 8 * NT) {
        float4 arr[8];
#pragma unroll
        for (int q = 0; q < 8; ++q) arr[q] = l4p[i + q * NT];
#pragma unroll
        for (int q = 0; q < 8; ++q)
#pragma unroll
            for (int j = 0; j < 4; ++j) {
                float x = __fmul_rn((&arr[q].x)[j], r);
                atomicAdd(&hc[mono_u32(x) >> BSHIFT], 1u);
                es += __expf(x);
            }
    }
    for (; i < V4; i += NT) {
        float4 A = l4p[i];
#pragma unroll
        for (int j = 0; j < 4; ++j) {
            float x = __fmul_rn((&A.x)[j], r);
            atomicAdd(&hc[mono_u32(x) >> BSHIFT], 1u);
            es += __expf(x);
        }
    }
    for (int v = (V4 << 2) + tid; v < V; v += NT) {
        float x = __fmul_rn(lrow[v], r);
        atomicAdd(&hc[mono_u32(x) >> BSHIFT], 1u);
        es += __expf(x);
    }
    for (int off = 32; off; off >>= 1) es += __shfl_down(es, off);
    if ((tid & 63) == 0) atomicAdd(&esum_s, es);
    __syncthreads();

    // ---- penalty corrections (<=200/row): move buckets, fix sum(exp) ----
    float pres = pres_v[row], freq = freq_v[row];
    int active = (pres >= 1e-5f) || (freq >= 1e-5f);
    float corr = 0.0f;
    if (active) {
        for (int s = tid; s < HS; s += NT) {
            int v = hkey[s];
            if (v >= 0) {
                int c = hval[s];
                float l = lrow[v];
                float x0 = __fmul_rn(l, r);
                float xp = compute_x(l, c, pres, freq, t);
                unsigned b0 = mono_u32(x0) >> BSHIFT;
                unsigned bp = mono_u32(xp) >> BSHIFT;
                if (b0 != bp) { atomicSub(&hc[b0], 1u); atomicAdd(&hc[bp], 1u); }
                corr += __expf(xp) - __expf(x0);
            }
        }
    }
    for (int off = 32; off; off >>= 1) corr += __shfl_down(corr, off);
    if ((tid & 63) == 0) atomicAdd(&corr_s, corr);
    __syncthreads();

    // ---- Phase B: coarse suffix scan (8/thread serial + block scan) ----
    const int BPT = NB / NT;   // 8
    int base = tid * BPT;
    int acc = 0;
#pragma unroll
    for (int q = BPT - 1; q >= 0; --q) { acc += (int)hc[base + q]; hc[base + q] = (unsigned)acc; }
    sct[tid] = acc;
    __syncthreads();
    {
        int* a = sct; int* b2 = sct2;
        for (int s = 1; s < NT; s <<= 1) {
            int v = a[tid] + ((tid + s < NT) ? a[tid + s] : 0);
            __syncthreads();
            b2[tid] = v;
            __syncthreads();
            int* tmp = a; a = b2; b2 = tmp;
        }
        int above = (tid < NT - 1) ? a[tid + 1] : 0;
        int k = topk_v[row];
        int best = -1;
#pragma unroll
        for (int q = BPT - 1; q >= 0; --q)
            if ((int)hc[base + q] + above >= k) { best = base + q; break; }
        if (best >= 0) atomicMax(&bstar_s, best);
    }
    __syncthreads();
    int bst = bstar_s - 2;               // slack: approx-vs-exact bucketing
    if (bst < 0) bst = 0;
    float Sp = esum_s + corr_s;
    __syncthreads();                     // hc dead; region A becomes skey

    // ---- Phase C: stream 2 — zero-fill out + compact candidates ----
    float4* o4p = (float4*)(out + (size_t)row * V);
    const float4 z4 = make_float4(0.f, 0.f, 0.f, 0.f);
    i = tid;
    for (; i + 7 * NT < V4; i += 8 * NT) {
        float4 arr[8];
#pragma unroll
        for (int q = 0; q < 8; ++q) arr[q] = l4p[i + q * NT];
#pragma unroll
        for (int q = 0; q < 8; ++q) o4p[i + q * NT] = z4;
#pragma unroll
        for (int q = 0; q < 8; ++q) {
            int vb = (i + q * NT) << 2;
#pragma unroll
            for (int j = 0; j < 4; ++j) {
                float l = (&arr[q].x)[j];
                unsigned ua = mono_u32(__fmul_rn(l, r));
                if ((int)(ua >> BSHIFT) >= bst) {
                    unsigned ue = mono_u32(__fdiv_rn(l, t));   // exact key
                    int pos = atomicAdd(&lcnt_s, 1);
                    if (pos < CAP)
                        skey[pos] = ((ull)ue << 32) | (unsigned)~(unsigned)(vb + j);
                }
            }
        }
    }
    for (; i < V4; i += NT) {
        float4 A = l4p[i];
        o4p[i] = z4;
#pragma unroll
        for (int j = 0; j < 4; ++j) {
            float l = (&A.x)[j];
            unsigned ua = mono_u32(__fmul_rn(l, r));
            if ((int)(ua >> BSHIFT) >= bst) {
                unsigned ue = mono_u32(__fdiv_rn(l, t));
                int pos = atomicAdd(&lcnt_s, 1);
                if (pos < CAP)
                    skey[pos] = ((ull)ue << 32) | (unsigned)~(unsigned)((i << 2) + j);
            }
        }
    }
    for (int v = (V4 << 2) + tid; v < V; v += NT) {
        float l = lrow[v];
        out[(size_t)row * V + v] = 0.0f;
        unsigned ua = mono_u32(__fmul_rn(l, r));
        if ((int)(ua >> BSHIFT) >= bst) {
            unsigned ue = mono_u32(__fdiv_rn(l, t));
            int pos = atomicAdd(&lcnt_s, 1);
            if (pos < CAP)
                skey[pos] = ((ull)ue << 32) | (unsigned)~(unsigned)v;
        }
    }
    __syncthreads();
    int count = lcnt_s; if (count > CAP) count = CAP;
    int k = topk_v[row];

    // ---- Phase D: exact penalized keys, refined cut, prune ----
    if (active) {
        for (int j = tid; j < count; j += NT) {
            unsigned idx = ~(unsigned)(skey[j] & 0xffffffffull);
            unsigned h = (idx * 2654435761u) >> 23;
            int c = 0;
            while (true) {
                int kk = hkey[h];
                if (kk == (int)idx) { c = hval[h]; break; }
                if (kk == -1) break;
                h = (h + 1) & HM;
            }
            if (c > 0) {
                float xp = compute_x(lrow[idx], c, pres, freq, t);
                skey[j] = ((ull)mono_u32(xp) << 32) | (unsigned)~idx;
            }
        }
    }
    __syncthreads();
    for (int g = tid; g < NRB; g += NT) rh[g] = 0u;
    __syncthreads();
    int gmin = bst << 6;
    for (int j = tid; j < count; j += NT) {
        unsigned u = (unsigned)(skey[j] >> 32);
        int rel = (int)(u >> 13) - gmin;
        rel = rel < 0 ? 0 : (rel > NRB - 1 ? NRB - 1 : rel);
        atomicAdd(&rh[rel], 1u);
    }
    __syncthreads();
    {   // refined suffix scan (2/thread serial + block scan)
        int b2i = tid * 2;
        int a2 = (int)rh[b2i + 1];
        rh[b2i + 1] = (unsigned)a2;
        a2 += (int)rh[b2i];
        rh[b2i] = (unsigned)a2;
        sct[tid] = a2;
        __syncthreads();
        int* a = sct; int* b2 = sct2;
        for (int s = 1; s < NT; s <<= 1) {
            int v = a[tid] + ((tid + s < NT) ? a[tid + s] : 0);
            __syncthreads();
            b2[tid] = v;
            __syncthreads();
            int* tmp = a; a = b2; b2 = tmp;
        }
        int above = (tid < NT - 1) ? a[tid + 1] : 0;
        int best = -1;
        if ((int)rh[b2i + 1] + above >= k) best = b2i + 1;
        else if ((int)rh[b2i] + above >= k) best = b2i;
        if (best >= 0) atomicMax(&rb_s, best);
    }
    __syncthreads();
    int rb = rb_s;
    for (int j = tid; j < count; j += NT) {
        unsigned u = (unsigned)(skey[j] >> 32);
        int rel = (int)(u >> 13) - gmin;
        rel = rel < 0 ? 0 : (rel > NRB - 1 ? NRB - 1 : rel);
        if (rel >= rb) {
            int pos = atomicAdd(&pcnt_s, 1);
            if (pos < PCAP) tmpc[pos] = skey[j];
        }
    }
    __syncthreads();
    int count2 = pcnt_s;
    if (count2 <= PCAP) {   // pruned set is rank-preserving (upward-closed in u)
        for (int j = tid; j < count2; j += NT) skey[j] = tmpc[j];
        count = count2;
    }
    __syncthreads();

    // ---- Phase E: bitonic sort descending on (u desc, idx asc) ----
    int m = 1; while (m < count) m <<= 1;
    for (int j = count + tid; j < m; j += NT) skey[j] = 0ull;
    __syncthreads();
    for (int kk = 2; kk <= m; kk <<= 1) {
        for (int jj = kk >> 1; jj > 0; jj >>= 1) {
            for (int i2 = tid; i2 < m; i2 += NT) {
                int ixj = i2 ^ jj;
                if (ixj > i2) {
                    ull A = skey[i2], B = skey[ixj];
                    bool up = ((i2 & kk) != 0);
                    if ((A > B) == up) { skey[i2] = B; skey[ixj] = A; }
                }
            }
            __syncthreads();
        }
    }

    // ---- Phase F: exp, exact cumsum, top-k/top-p select, scatter ----
    for (int j = tid; j < CAP; j += NT)
        se[j] = (j < count) ? __expf(inv_mono((unsigned)(skey[j] >> 32))) : 0.0f;
    __syncthreads();
    int j0 = tid << 2;
    float e0 = se[j0], e1 = se[j0 + 1], e2 = se[j0 + 2], e3 = se[j0 + 3];
    float c0 = e0, c1 = c0 + e1, c2 = c1 + e2, c3 = c2 + e3;
    bs1[tid] = c3;
    __syncthreads();
    float* a = bs1; float* b2 = bs2;
    for (int s = 1; s < NT; s <<= 1) {
        float v = a[tid] + ((tid >= s) ? a[tid - s] : 0.0f);
        __syncthreads();
        b2[tid] = v;
        __syncthreads();
        float* tmp = a; a = b2; b2 = tmp;
    }
    float pre = (tid > 0) ? a[tid - 1] : 0.0f;

    float pS = topp_v[row] * Sp;
    float inc[4] = {pre + c0, pre + c1, pre + c2, pre + c3};
    float ee[4] = {e0, e1, e2, e3};
#pragma unroll
    for (int q = 0; q < 4; ++q) {
        int j = j0 + q;
        if (j < count) {
            float e = ee[q];
            float excl = __fsub_rn(inc[q], e);
            if ((j < k) && (excl <= pS)) {
                unsigned idx = ~(unsigned)(skey[j] & 0xffffffffull);
                out[(size_t)row * V + idx] = __fdiv_rn(e, Sp);
            }
        }
    }
}

extern "C" void kernel_launch(void* const* d_in, const int* in_sizes, int n_in,
                              void* d_out, int out_size, void* d_ws, size_t ws_size,
                              hipStream_t stream) {
    const float* logits = (const float*)d_in[0];
    const float* pres   = (const float*)d_in[1];
    const float* freq   = (const float*)d_in[2];
    const float* temps  = (const float*)d_in[3];
    const float* topps  = (const float*)d_in[4];
    const int*   tokens = (const int*)d_in[5];
    const int*   topks  = (const int*)d_in[6];
    int N = in_sizes[1];
    int V = in_sizes[0] / N;
    int H = in_sizes[5] / N;
    float* out = (float*)d_out;

    k_fused<<<N, NT, 0, stream>>>(logits, tokens, pres, freq, temps, topps,
                                  topks, V, H, out);
}